// Round 4
// baseline (1329.423 us; speedup 1.0000x reference)
//
#include <hip/hip_runtime.h>
#include <math.h>

#define S_ 2048
#define N_ 256
#define MID_ 512
#define NB_ 8
#define JSL_ 64   // MID_/NB_
#define LN_EPS_ 1e-5f

__device__ __forceinline__ float gelu_exact(float x){
    return 0.5f * x * (1.0f + erff(x * 0.70710678118654752440f));
}

// ---------------- setup kernels ----------------

__global__ void k_init(const float* __restrict__ xs, const float* __restrict__ gamma,
                       const float* __restrict__ w2,
                       float* __restrict__ probs, float* __restrict__ w2T,
                       float* __restrict__ gw2, unsigned int* __restrict__ wmask32,
                       int* __restrict__ flags)
{
    int idx = blockIdx.x * blockDim.x + threadIdx.x;   // grid covers 524288
    if (idx < S_*N_) probs[idx] = xs[idx];
    if (idx < MID_*N_) {
        int j = idx / N_, c = idx % N_;
        float v = w2[idx];
        gw2[idx] = gamma[j] * v;
        w2T[c*MID_ + j] = v;
    }
    if (idx < (N_*N_)/4) wmask32[idx] = 0u;
    if (idx < NB_*32) flags[idx] = 0;
}

__global__ void k_mask(const int* __restrict__ ids, unsigned char* __restrict__ wmask){
    int i = blockIdx.x*blockDim.x + threadIdx.x;       // 524288 = S_*N_
    if (i < S_*N_){
        int t = i & (N_-1);        // i = k*256 + t  (row-major ids_ary[k][t])
        int c = ids[i];
        wmask[t*N_ + c] = 1;       // benign write race, value always 1
    }
}

// pack byte-mask into bit-mask: wmaskb[t*8 + c/32] bit (c%32)
__global__ void k_pack(const unsigned char* __restrict__ wmask,
                       unsigned int* __restrict__ wmaskb){
    int d = blockIdx.x*blockDim.x + threadIdx.x;       // 2048 total
    if (d < (N_*N_)/32){
        const unsigned int* p = (const unsigned int*)(wmask + d*32);
        unsigned int bits = 0;
        #pragma unroll
        for (int k = 0; k < 8; k++){
            unsigned int v = p[k];
            if (v & 0x000000FFu) bits |= 1u << (k*4 + 0);
            if (v & 0x0000FF00u) bits |= 1u << (k*4 + 1);
            if (v & 0x00FF0000u) bits |= 1u << (k*4 + 2);
            if (v & 0xFF000000u) bits |= 1u << (k*4 + 3);
        }
        wmaskb[d] = bits;
    }
}

__global__ void k_ab(const float* __restrict__ gamma, const float* __restrict__ beta,
                     const float* __restrict__ w2, const float* __restrict__ b2,
                     float* __restrict__ A, float* __restrict__ Bc){
    __shared__ float ra[256], rb[256];
    int c = blockIdx.x, tid = threadIdx.x;
    float a = 0.f, b = 0.f;
    for (int j = tid; j < MID_; j += 256){
        float v = w2[j*N_ + c];
        a += gamma[j]*v;
        b += beta[j]*v;
    }
    ra[tid] = a; rb[tid] = b; __syncthreads();
    for (int off = 128; off > 0; off >>= 1){
        if (tid < off){ ra[tid] += ra[tid+off]; rb[tid] += rb[tid+off]; }
        __syncthreads();
    }
    if (tid == 0){ A[c] = ra[0]; Bc[c] = rb[0] + b2[c]; }
}

// ---------------- exact full-row step (t = 0..2) ----------------

__global__ __launch_bounds__(256) void k_full_rows(
    const float* __restrict__ probs, const float* __restrict__ w1,
    const float* __restrict__ b1, const float* __restrict__ gamma,
    const float* __restrict__ beta, const float* __restrict__ w2T,
    const float* __restrict__ b2, const int* __restrict__ ids,
    float* __restrict__ ps, int t)
{
    __shared__ float prow[8][N_];
    int tid = threadIdx.x;
    int r0 = blockIdx.x * 8;
    for (int i = tid; i < 8*N_; i += 256)
        prow[i>>8][i&255] = probs[(r0 + (i>>8))*N_ + (i&255)];
    __syncthreads();
    int r = tid >> 5, jg = tid & 31;      // 8 rows x 32 threads
    float h[16];
    #pragma unroll
    for (int m = 0; m < 16; m++) h[m] = b1[jg + 32*m];
    for (int c = 0; c < N_; c++){
        float p = prow[r][c];
        const float* w1r = w1 + c*MID_;
        #pragma unroll
        for (int m = 0; m < 16; m++) h[m] = fmaf(p, w1r[jg + 32*m], h[m]);
    }
    float s1 = 0.f, s2 = 0.f;
    #pragma unroll
    for (int m = 0; m < 16; m++){
        float g = gelu_exact(h[m]);
        h[m] = g; s1 += g; s2 += g*g;
    }
    #pragma unroll
    for (int off = 16; off > 0; off >>= 1){
        s1 += __shfl_xor(s1, off, 32);
        s2 += __shfl_xor(s2, off, 32);
    }
    float mu  = s1 * (1.f/MID_);
    float var = s2 * (1.f/MID_) - mu*mu;
    float inv = rsqrtf(var + LN_EPS_);
    int rg = r0 + r;
    int id = ids[rg*N_ + t];
    const float* wrow = w2T + id*MID_;
    float acc = 0.f;
    #pragma unroll
    for (int m = 0; m < 16; m++){
        int j = jg + 32*m;
        float hn = (h[m] - mu)*inv*gamma[j] + beta[j];
        acc = fmaf(hn, wrow[j], acc);
    }
    #pragma unroll
    for (int off = 16; off > 0; off >>= 1) acc += __shfl_xor(acc, off, 32);
    if (jg == 0) ps[rg] = 1.f/(1.f + expf(-(acc + b2[id])));
}

// last-k-wins scatter (numpy fancy-assignment semantics)
__global__ void k_scatter(const int* __restrict__ ids, const float* __restrict__ ps,
                          float* __restrict__ newval, int* __restrict__ wrote, int t){
    __shared__ int lastk[N_];
    int tid = threadIdx.x;
    lastk[tid] = -1;
    __syncthreads();
    for (int k = tid; k < S_; k += 256) atomicMax(&lastk[ids[k*N_ + t]], k);
    __syncthreads();
    int lk = lastk[tid];
    wrote[tid] = (lk >= 0) ? 1 : 0;
    if (lk >= 0) newval[tid] = ps[lk];
}

__global__ void k_apply(float* __restrict__ probs, const float* __restrict__ newval,
                        const int* __restrict__ wrote){
    int idx = blockIdx.x*blockDim.x + threadIdx.x;     // 524288
    int c = idx & (N_-1);
    if (wrote[c]) probs[idx] = newval[c];
}

// ---------------- persistent single-row fast path (t = 3..255) ----------------
// 8 blocks (any XCD placement). Per step, each block exports its 256 partial
// matvec values + 2 LN-stat partials (plain stores), publishes with ONE
// release-store, consumers poll with RMW fetch_add(0) (executes at the device
// coherence point -- cannot read stale caches, cannot hang), then ONE acquire
// fence + plain imports.

__global__ __launch_bounds__(512) void k_fast(
    const float* __restrict__ w1, const float* __restrict__ b1,
    const float* __restrict__ gw2, const float* __restrict__ A,
    const float* __restrict__ Bc, const unsigned int* __restrict__ wmaskb,
    const float* __restrict__ probs, float* __restrict__ partials,
    int* __restrict__ flags, float* __restrict__ commonFinal, int t0)
{
    __shared__ float w1s[N_*JSL_];       // [c][jj], 64 KiB
    __shared__ float gw2s[JSL_*N_];      // [jj][c], 64 KiB
    __shared__ float common[N_];
    __shared__ float hpart[8][JSL_];
    __shared__ float gvals[JSL_];
    __shared__ float pr[NB_][2];
    __shared__ unsigned int wbits[(N_*N_)/32];  // 8 KiB bit-mask

    int tid = threadIdx.x, b = blockIdx.x;
    int j0 = b * JSL_;

    for (int i = tid; i < N_*JSL_; i += 512){
        int c = i >> 6, jj = i & 63;
        w1s[i] = w1[c*MID_ + j0 + jj];
    }
    for (int i = tid; i < JSL_*N_; i += 512){
        int jj = i >> 8, c = i & 255;
        gw2s[i] = gw2[(j0 + jj)*N_ + c];
    }
    for (int i = tid; i < (N_*N_)/32; i += 512) wbits[i] = wmaskb[i];
    if (tid < N_) common[tid] = probs[tid];            // all rows identical by t0
    float Ac  = (tid < N_)   ? A[tid]      : 0.f;
    float Bcc = (tid < N_)   ? Bc[tid]     : 0.f;
    float b1v = (tid < JSL_) ? b1[j0+tid]  : 0.f;
    __syncthreads();

    float st1 = 0.f, st2 = 0.f;          // LN-stat partials (valid in tid 0)
    for (int t = t0; t < N_; t++){
        int slot = t & 1;
        float* myp = partials + (slot*NB_ + b)*264;
        // P0: partial h for own j-slice (8 c-groups x 64 j)
        {
            int jj = tid & 63, cg = tid >> 6;
            int cbase = cg * 32;
            float acc = 0.f;
            #pragma unroll 8
            for (int cc = 0; cc < 32; cc++)
                acc = fmaf(common[cbase + cc], w1s[(cbase + cc)*JSL_ + jj], acc);
            hpart[cg][jj] = acc;
        }
        __syncthreads();
        // P1: reduce h, gelu, LN-stat partials
        if (tid < JSL_){
            float h = b1v;
            #pragma unroll
            for (int cg = 0; cg < 8; cg++) h += hpart[cg][tid];
            float g = gelu_exact(h);
            gvals[tid] = g;
            float s1 = g, s2 = g*g;
            #pragma unroll
            for (int off = 32; off > 0; off >>= 1){
                s1 += __shfl_xor(s1, off, 64);
                s2 += __shfl_xor(s2, off, 64);
            }
            if (tid == 0){ st1 = s1; st2 = s2; }
        }
        __syncthreads();
        // P2: partial matvec for own slice; export (plain stores)
        if (tid < N_){
            float p1 = 0.f;
            #pragma unroll 8
            for (int jj = 0; jj < JSL_; jj++)
                p1 = fmaf(gvals[jj], gw2s[jj*N_ + tid], p1);
            myp[tid] = p1;
        }
        if (tid == 0){ myp[256] = st1; myp[257] = st2; }
        asm volatile("s_waitcnt vmcnt(0)" ::: "memory");  // own stores at L2
        __syncthreads();                                   // all threads' stores done
        // publish: ONE release-store per block
        if (tid == 0)
            __hip_atomic_store(&flags[b*32], t + 1, __ATOMIC_RELEASE,
                               __HIP_MEMORY_SCOPE_AGENT);
        // poll: RMW executes at coherence point -- stale-proof
        if (tid < NB_){
            while (__hip_atomic_fetch_add(&flags[tid*32], 0, __ATOMIC_RELAXED,
                                          __HIP_MEMORY_SCOPE_AGENT) < t + 1) {}
        }
        __syncthreads();                 // all 8 flags seen by the block
        // ONE acquire fence for the whole import phase
        __builtin_amdgcn_fence(__ATOMIC_ACQUIRE, "agent");
        if (tid < NB_){
            pr[tid][0] = partials[(slot*NB_ + tid)*264 + 256];
            pr[tid][1] = partials[(slot*NB_ + tid)*264 + 257];
        }
        __syncthreads();
        // P4: redundant finish: stats, s[c], sigmoid, common update
        if (tid < N_){
            const float* pp = partials + slot*NB_*264 + tid;
            float s1 = 0.f;
            #pragma unroll
            for (int bb = 0; bb < NB_; bb++) s1 += pp[bb*264];
            float S1 = 0.f, S2 = 0.f;
            #pragma unroll
            for (int bb = 0; bb < NB_; bb++){ S1 += pr[bb][0]; S2 += pr[bb][1]; }
            float mu  = S1 * (1.f/MID_);
            float var = S2 * (1.f/MID_) - mu*mu;
            float inv = rsqrtf(var + LN_EPS_);
            float s = inv*(s1 - mu*Ac) + Bcc;
            float o = 1.f/(1.f + expf(-s));
            if ((wbits[(t<<3) + (tid>>5)] >> (tid&31)) & 1u) common[tid] = o;
        }
        __syncthreads();
    }
    if (b == 0 && tid < N_) commonFinal[tid] = common[tid];
}

__global__ void k_out(const float* __restrict__ commonFinal, float* __restrict__ out){
    int idx = blockIdx.x*blockDim.x + threadIdx.x;     // 524288
    out[idx] = commonFinal[idx & (N_-1)];
}

// ---------------- launch ----------------

extern "C" void kernel_launch(void* const* d_in, const int* in_sizes, int n_in,
                              void* d_out, int out_size, void* d_ws, size_t ws_size,
                              hipStream_t stream)
{
    const float* xs    = (const float*)d_in[0];
    const int*   ids   = (const int*)  d_in[1];
    const float* w1    = (const float*)d_in[2];
    const float* b1    = (const float*)d_in[3];
    const float* gamma = (const float*)d_in[4];
    const float* beta  = (const float*)d_in[5];
    const float* w2    = (const float*)d_in[6];
    const float* b2    = (const float*)d_in[7];
    float* out = (float*)d_out;

    float* ws      = (float*)d_ws;
    float* probs   = ws;                     // 524288 f32
    float* w2T     = probs + S_*N_;          // 131072
    float* gw2     = w2T + N_*MID_;          // 131072
    float* A       = gw2 + MID_*N_;          // 256
    float* Bc      = A + N_;                 // 256
    float* ps      = Bc + N_;                // 2048
    float* newval  = ps + S_;                // 256
    int*   wrote   = (int*)(newval + N_);    // 256
    unsigned char* wmask = (unsigned char*)(wrote + N_);  // 65536 B
    float* partials = (float*)(wmask + N_*N_);            // 16*264 f32
    int*   flags    = (int*)(partials + 16*264);          // 8*32 ints (128B/flag)
    unsigned int* wmaskb = (unsigned int*)(flags + NB_*32);  // 2048 uints
    float* commonFinal = (float*)(wmaskb + (N_*N_)/32);   // 256

    k_init<<<2048, 256, 0, stream>>>(xs, gamma, w2, probs, w2T, gw2,
                                     (unsigned int*)wmask, flags);
    k_mask<<<2048, 256, 0, stream>>>(ids, wmask);
    k_ab<<<256, 256, 0, stream>>>(gamma, beta, w2, b2, A, Bc);
    k_pack<<<8, 256, 0, stream>>>(wmask, wmaskb);

    for (int t = 0; t < 3; t++){
        k_full_rows<<<256, 256, 0, stream>>>(probs, w1, b1, gamma, beta, w2T, b2,
                                             ids, ps, t);
        k_scatter<<<1, 256, 0, stream>>>(ids, ps, newval, wrote, t);
        k_apply<<<2048, 256, 0, stream>>>(probs, newval, wrote);
    }

    k_fast<<<NB_, 512, 0, stream>>>(w1, b1, gw2, A, Bc, wmaskb, probs,
                                    partials, flags, commonFinal, 3);
    k_out<<<2048, 256, 0, stream>>>(commonFinal, out);
}

// Round 5
// 929.006 us; speedup vs baseline: 1.4310x; 1.4310x over previous
//
#include <hip/hip_runtime.h>
#include <math.h>

#define S_ 2048
#define N_ 256
#define MID_ 512
#define NB_ 8
#define JSL_ 64   // MID_/NB_
#define LN_EPS_ 1e-5f
#define NBLK_ 64          // blocks launched for the election
#define NSTEP_ 253        // fast-path steps (t = 3..255)
#define SLOT_F_ 2112      // floats per step slot (8 roles x 264); 8448 B, 128-B aligned
#define CTRW_ 32          // ints per step-counter line (128 B)

__device__ __forceinline__ float gelu_exact(float x){
    return 0.5f * x * (1.0f + erff(x * 0.70710678118654752440f));
}

// ---- local-L2 RMW helpers (no sc1 -> execute at the XCD's L2; identical
// encoding+address for producer and consumer => they meet at the same cache
// level whatever that level is => hang-proof, stale-proof) ----
__device__ __forceinline__ void atomic_inc_l2(int* p){
    int one = 1;
    asm volatile("global_atomic_add %0, %1, off" :: "v"(p), "v"(one) : "memory");
}
__device__ __forceinline__ int atomic_read_l2(int* p){
    int v; int zero = 0;
    asm volatile("global_atomic_add %0, %1, %2, off sc0\n\ts_waitcnt vmcnt(0)"
                 : "=v"(v) : "v"(p), "v"(zero) : "memory");
    return v;
}

// ---------------- setup kernels ----------------

__global__ void k_init(const float* __restrict__ xs, const float* __restrict__ gamma,
                       const float* __restrict__ w2,
                       float* __restrict__ probs, float* __restrict__ w2T,
                       float* __restrict__ gw2, unsigned int* __restrict__ wmask32,
                       int* __restrict__ ctrall, int* __restrict__ winner)
{
    int idx = blockIdx.x * blockDim.x + threadIdx.x;   // grid covers 524288
    if (idx < S_*N_) probs[idx] = xs[idx];
    if (idx < MID_*N_) {
        int j = idx / N_, c = idx % N_;
        float v = w2[idx];
        gw2[idx] = gamma[j] * v;
        w2T[c*MID_ + j] = v;
    }
    if (idx < (N_*N_)/4) wmask32[idx] = 0u;
    if (idx < NSTEP_*CTRW_ + 8) ctrall[idx] = 0;       // step ctrs + xcd cnt
    if (idx == 0) *winner = -1;
}

__global__ void k_mask(const int* __restrict__ ids, unsigned char* __restrict__ wmask){
    int i = blockIdx.x*blockDim.x + threadIdx.x;       // 524288 = S_*N_
    if (i < S_*N_){
        int t = i & (N_-1);        // i = k*256 + t  (row-major ids_ary[k][t])
        int c = ids[i];
        wmask[t*N_ + c] = 1;       // benign write race, value always 1
    }
}

// pack byte-mask into bit-mask: wmaskb[t*8 + c/32] bit (c%32)
__global__ void k_pack(const unsigned char* __restrict__ wmask,
                       unsigned int* __restrict__ wmaskb){
    int d = blockIdx.x*blockDim.x + threadIdx.x;       // 2048 total
    if (d < (N_*N_)/32){
        const unsigned int* p = (const unsigned int*)(wmask + d*32);
        unsigned int bits = 0;
        #pragma unroll
        for (int k = 0; k < 8; k++){
            unsigned int v = p[k];
            if (v & 0x000000FFu) bits |= 1u << (k*4 + 0);
            if (v & 0x0000FF00u) bits |= 1u << (k*4 + 1);
            if (v & 0x00FF0000u) bits |= 1u << (k*4 + 2);
            if (v & 0xFF000000u) bits |= 1u << (k*4 + 3);
        }
        wmaskb[d] = bits;
    }
}

__global__ void k_ab(const float* __restrict__ gamma, const float* __restrict__ beta,
                     const float* __restrict__ w2, const float* __restrict__ b2,
                     float* __restrict__ A, float* __restrict__ Bc){
    __shared__ float ra[256], rb[256];
    int c = blockIdx.x, tid = threadIdx.x;
    float a = 0.f, b = 0.f;
    for (int j = tid; j < MID_; j += 256){
        float v = w2[j*N_ + c];
        a += gamma[j]*v;
        b += beta[j]*v;
    }
    ra[tid] = a; rb[tid] = b; __syncthreads();
    for (int off = 128; off > 0; off >>= 1){
        if (tid < off){ ra[tid] += ra[tid+off]; rb[tid] += rb[tid+off]; }
        __syncthreads();
    }
    if (tid == 0){ A[c] = ra[0]; Bc[c] = rb[0] + b2[c]; }
}

// ---------------- exact full-row step (t = 0..2) ----------------

__global__ __launch_bounds__(256) void k_full_rows(
    const float* __restrict__ probs, const float* __restrict__ w1,
    const float* __restrict__ b1, const float* __restrict__ gamma,
    const float* __restrict__ beta, const float* __restrict__ w2T,
    const float* __restrict__ b2, const int* __restrict__ ids,
    float* __restrict__ ps, int t)
{
    __shared__ float prow[8][N_];
    int tid = threadIdx.x;
    int r0 = blockIdx.x * 8;
    for (int i = tid; i < 8*N_; i += 256)
        prow[i>>8][i&255] = probs[(r0 + (i>>8))*N_ + (i&255)];
    __syncthreads();
    int r = tid >> 5, jg = tid & 31;      // 8 rows x 32 threads
    float h[16];
    #pragma unroll
    for (int m = 0; m < 16; m++) h[m] = b1[jg + 32*m];
    for (int c = 0; c < N_; c++){
        float p = prow[r][c];
        const float* w1r = w1 + c*MID_;
        #pragma unroll
        for (int m = 0; m < 16; m++) h[m] = fmaf(p, w1r[jg + 32*m], h[m]);
    }
    float s1 = 0.f, s2 = 0.f;
    #pragma unroll
    for (int m = 0; m < 16; m++){
        float g = gelu_exact(h[m]);
        h[m] = g; s1 += g; s2 += g*g;
    }
    #pragma unroll
    for (int off = 16; off > 0; off >>= 1){
        s1 += __shfl_xor(s1, off, 32);
        s2 += __shfl_xor(s2, off, 32);
    }
    float mu  = s1 * (1.f/MID_);
    float var = s2 * (1.f/MID_) - mu*mu;
    float inv = rsqrtf(var + LN_EPS_);
    int rg = r0 + r;
    int id = ids[rg*N_ + t];
    const float* wrow = w2T + id*MID_;
    float acc = 0.f;
    #pragma unroll
    for (int m = 0; m < 16; m++){
        int j = jg + 32*m;
        float hn = (h[m] - mu)*inv*gamma[j] + beta[j];
        acc = fmaf(hn, wrow[j], acc);
    }
    #pragma unroll
    for (int off = 16; off > 0; off >>= 1) acc += __shfl_xor(acc, off, 32);
    if (jg == 0) ps[rg] = 1.f/(1.f + expf(-(acc + b2[id])));
}

// last-k-wins scatter (numpy fancy-assignment semantics)
__global__ void k_scatter(const int* __restrict__ ids, const float* __restrict__ ps,
                          float* __restrict__ newval, int* __restrict__ wrote, int t){
    __shared__ int lastk[N_];
    int tid = threadIdx.x;
    lastk[tid] = -1;
    __syncthreads();
    for (int k = tid; k < S_; k += 256) atomicMax(&lastk[ids[k*N_ + t]], k);
    __syncthreads();
    int lk = lastk[tid];
    wrote[tid] = (lk >= 0) ? 1 : 0;
    if (lk >= 0) newval[tid] = ps[lk];
}

__global__ void k_apply(float* __restrict__ probs, const float* __restrict__ newval,
                        const int* __restrict__ wrote){
    int idx = blockIdx.x*blockDim.x + threadIdx.x;     // 524288
    int c = idx & (N_-1);
    if (wrote[c]) probs[idx] = newval[c];
}

// ---------------- persistent single-row fast path (t = 3..255) ----------------
// 64 blocks launched; election (RMW-only: atomicAdd + atomicCAS, stale-proof)
// picks 8 co-resident blocks on ONE XCD as the team; rest exit. Team syncs
// through its shared XCD L2: plain stores (write-through, acked at L2 by
// vmcnt(0)) into a NEVER-REUSED per-step slot, then a local-L2 RMW counter.
// No fences, no wbl2/inv, no cache-flag semantics assumed.

__global__ __launch_bounds__(512) void k_fast(
    const float* __restrict__ w1, const float* __restrict__ b1,
    const float* __restrict__ gw2, const float* __restrict__ A,
    const float* __restrict__ Bc, const unsigned int* __restrict__ wmaskb,
    const float* __restrict__ probs, float* __restrict__ slots,
    int* __restrict__ ctr, int* __restrict__ cnt, int* __restrict__ winner,
    float* __restrict__ commonFinal, int t0)
{
    __shared__ int s_role;
    __shared__ float w1s[N_*JSL_];       // [c][jj], 64 KiB
    __shared__ float gw2s[JSL_*N_];      // [jj][c], 64 KiB
    __shared__ float common[N_];
    __shared__ float hpart[8][JSL_];
    __shared__ float gvals[JSL_];
    __shared__ float pr[NB_][2];
    __shared__ unsigned int wbits[(N_*N_)/32];  // 8 KiB bit-mask

    int tid = threadIdx.x;

    // ---- election: RMW-only, hang-proof ----
    if (tid == 0){
        int xcd;
        asm volatile("s_getreg_b32 %0, hwreg(HW_REG_XCC_ID)" : "=s"(xcd));
        xcd &= 7;
        int pos = atomicAdd(&cnt[xcd], 1);
        int role = -1;
        if (pos == NB_ - 1){                       // 8th block on this XCD
            int old = atomicCAS(winner, -1, xcd);
            if (old == -1) role = NB_ - 1;         // claimed: we are role 7
        } else if (pos < NB_ - 1){
            int w;
            while ((w = atomicCAS(winner, -2, -2)) == -1)  // RMW read
                __builtin_amdgcn_s_sleep(2);
            if (w == xcd) role = pos;              // our XCD won: role = pos
        }                                           // pos >= 8: not needed
        s_role = role;
    }
    __syncthreads();
    int role = s_role;
    if (role < 0) return;
    int j0 = role * JSL_;

    // ---- stage weights into LDS ----
    for (int i = tid; i < N_*JSL_; i += 512){
        int c = i >> 6, jj = i & 63;
        w1s[i] = w1[c*MID_ + j0 + jj];
    }
    for (int i = tid; i < JSL_*N_; i += 512){
        int jj = i >> 8, c = i & 255;
        gw2s[i] = gw2[(j0 + jj)*N_ + c];
    }
    for (int i = tid; i < (N_*N_)/32; i += 512) wbits[i] = wmaskb[i];
    if (tid < N_) common[tid] = probs[tid];            // all rows identical by t0
    float Ac  = (tid < N_)   ? A[tid]      : 0.f;
    float Bcc = (tid < N_)   ? Bc[tid]     : 0.f;
    float b1v = (tid < JSL_) ? b1[j0+tid]  : 0.f;
    __syncthreads();

    float st1 = 0.f, st2 = 0.f;          // LN-stat partials (valid in tid 0)
    for (int t = t0; t < N_; t++){
        float* slot = slots + (t - t0)*SLOT_F_;   // fresh slot every step
        float* myp  = slot + role*264;
        // P0: partial h for own j-slice (8 c-groups x 64 j)
        {
            int jj = tid & 63, cg = tid >> 6;
            int cbase = cg * 32;
            float acc = 0.f;
            #pragma unroll 8
            for (int cc = 0; cc < 32; cc++)
                acc = fmaf(common[cbase + cc], w1s[(cbase + cc)*JSL_ + jj], acc);
            hpart[cg][jj] = acc;
        }
        __syncthreads();
        // P1: reduce h, gelu, LN-stat partials
        if (tid < JSL_){
            float h = b1v;
            #pragma unroll
            for (int cg = 0; cg < 8; cg++) h += hpart[cg][tid];
            float g = gelu_exact(h);
            gvals[tid] = g;
            float s1 = g, s2 = g*g;
            #pragma unroll
            for (int off = 32; off > 0; off >>= 1){
                s1 += __shfl_xor(s1, off, 64);
                s2 += __shfl_xor(s2, off, 64);
            }
            if (tid == 0){ st1 = s1; st2 = s2; }
        }
        __syncthreads();
        // P2: partial matvec for own slice; export (plain stores -> shared L2)
        if (tid < N_){
            float p1 = 0.f;
            #pragma unroll 8
            for (int jj = 0; jj < JSL_; jj++)
                p1 = fmaf(gvals[jj], gw2s[jj*N_ + tid], p1);
            myp[tid] = p1;
        }
        if (tid == 0){ myp[256] = st1; myp[257] = st2; }
        asm volatile("s_waitcnt vmcnt(0)" ::: "memory");  // own stores acked at L2
        __syncthreads();                                   // all waves drained
        // publish + wait: local-L2 RMW counter
        int* c_t = ctr + (t - t0)*CTRW_;
        if (tid == 0){
            atomic_inc_l2(c_t);
            while (atomic_read_l2(c_t) < NB_) {}
        }
        __syncthreads();
        // import: plain loads of a never-before-touched slot (L1-fresh)
        if (tid < NB_){
            pr[tid][0] = slot[tid*264 + 256];
            pr[tid][1] = slot[tid*264 + 257];
        }
        __syncthreads();
        // P4: redundant finish: stats, s[c], sigmoid, common update
        if (tid < N_){
            const float* pp = slot + tid;
            float s1 = 0.f;
            #pragma unroll
            for (int bb = 0; bb < NB_; bb++) s1 += pp[bb*264];
            float S1 = 0.f, S2 = 0.f;
            #pragma unroll
            for (int bb = 0; bb < NB_; bb++){ S1 += pr[bb][0]; S2 += pr[bb][1]; }
            float mu  = S1 * (1.f/MID_);
            float var = S2 * (1.f/MID_) - mu*mu;
            float inv = rsqrtf(var + LN_EPS_);
            float s = inv*(s1 - mu*Ac) + Bcc;
            float o = 1.f/(1.f + expf(-s));
            if ((wbits[(t<<3) + (tid>>5)] >> (tid&31)) & 1u) common[tid] = o;
        }
        __syncthreads();
    }
    if (role == 0 && tid < N_) commonFinal[tid] = common[tid];
}

__global__ void k_out(const float* __restrict__ commonFinal, float* __restrict__ out){
    int idx = blockIdx.x*blockDim.x + threadIdx.x;     // 524288
    out[idx] = commonFinal[idx & (N_-1)];
}

// ---------------- launch ----------------

extern "C" void kernel_launch(void* const* d_in, const int* in_sizes, int n_in,
                              void* d_out, int out_size, void* d_ws, size_t ws_size,
                              hipStream_t stream)
{
    const float* xs    = (const float*)d_in[0];
    const int*   ids   = (const int*)  d_in[1];
    const float* w1    = (const float*)d_in[2];
    const float* b1    = (const float*)d_in[3];
    const float* gamma = (const float*)d_in[4];
    const float* beta  = (const float*)d_in[5];
    const float* w2    = (const float*)d_in[6];
    const float* b2    = (const float*)d_in[7];
    float* out = (float*)d_out;

    float* ws      = (float*)d_ws;
    float* probs   = ws;                     // 524288 f32
    // slots alias probs[2048:] + w2T (both dead during k_fast):
    float* slots   = ws + 2048;              // 253*2112 = 534336 f32, ends 536384
    float* w2T     = ws + 524288;            // 131072 (used only before k_fast)
    float* gw2     = ws + 655360;            // 131072
    float* A       = ws + 786432;            // 256
    float* Bc      = ws + 786688;            // 256
    float* ps      = ws + 786944;            // 2048
    float* newval  = ws + 788992;            // 256
    int*   wrote   = (int*)(ws + 789248);    // 256
    unsigned char* wmask = (unsigned char*)(ws + 789504);   // 65536 B -> ends 805888
    unsigned int* wmaskb = (unsigned int*)(ws + 805888);    // 2048 -> ends 807936
    int*   ctrall  = (int*)(ws + 807936);    // 253*32 + 8 = 8104 ints
    int*   ctr     = ctrall;                 // per-step counters
    int*   cnt     = ctrall + NSTEP_*CTRW_;  // 8 per-XCD counters
    int*   winner  = cnt + 8;                // 1
    float* commonFinal = ws + 816064;        // 256 -> ends 816320 (~3.27 MB)

    k_init<<<2048, 256, 0, stream>>>(xs, gamma, w2, probs, w2T, gw2,
                                     (unsigned int*)wmask, ctrall, winner);
    k_mask<<<2048, 256, 0, stream>>>(ids, wmask);
    k_ab<<<256, 256, 0, stream>>>(gamma, beta, w2, b2, A, Bc);
    k_pack<<<8, 256, 0, stream>>>(wmask, wmaskb);

    for (int t = 0; t < 3; t++){
        k_full_rows<<<256, 256, 0, stream>>>(probs, w1, b1, gamma, beta, w2T, b2,
                                             ids, ps, t);
        k_scatter<<<1, 256, 0, stream>>>(ids, ps, newval, wrote, t);
        k_apply<<<2048, 256, 0, stream>>>(probs, newval, wrote);
    }

    k_fast<<<NBLK_, 512, 0, stream>>>(w1, b1, gw2, A, Bc, wmaskb, probs, slots,
                                      ctr, cnt, winner, commonFinal, 3);
    k_out<<<2048, 256, 0, stream>>>(commonFinal, out);
}

// Round 6
// 828.126 us; speedup vs baseline: 1.6053x; 1.1218x over previous
//
#include <hip/hip_runtime.h>
#include <math.h>

#define S_ 2048
#define N_ 256
#define MID_ 512
#define NB_ 8
#define JSL_ 64   // MID_/NB_
#define LN_EPS_ 1e-5f
#define NBLK_ 64          // blocks launched for the election
#define NSTEP_ 253        // fast-path steps (t = 3..255)
#define BSTRIDE_ 288      // floats per role payload (256 + 2 stats + pad; 9 lines)
#define SLOT_F_ (NB_*BSTRIDE_)   // 2304 floats per step slot
#define CTRW_ 32          // ints per step-counter line (128 B)

typedef float f32x4 __attribute__((ext_vector_type(4)));
typedef float f32x2 __attribute__((ext_vector_type(2)));

__device__ __forceinline__ float gelu_exact(float x){
    return 0.5f * x * (1.0f + erff(x * 0.70710678118654752440f));
}

// ---- local-L2 RMW helpers (r5-proven) ----
__device__ __forceinline__ void atomic_inc_l2(int* p){
    int one = 1;
    asm volatile("global_atomic_add %0, %1, off" :: "v"(p), "v"(one) : "memory");
}
__device__ __forceinline__ int atomic_read_l2(int* p){
    int v; int zero = 0;
    asm volatile("global_atomic_add %0, %1, %2, off sc0\n\ts_waitcnt vmcnt(0)"
                 : "=v"(v) : "v"(p), "v"(zero) : "memory");
    return v;
}

// ---------------- setup kernels ----------------

__global__ void k_init(const float* __restrict__ xs, const float* __restrict__ gamma,
                       const float* __restrict__ w2,
                       float* __restrict__ probs, float* __restrict__ w2T,
                       float* __restrict__ gw2, unsigned int* __restrict__ wmask32,
                       int* __restrict__ ctrall, int* __restrict__ winner)
{
    int idx = blockIdx.x * blockDim.x + threadIdx.x;   // grid covers 524288
    if (idx < S_*N_) probs[idx] = xs[idx];
    if (idx < MID_*N_) {
        int j = idx / N_, c = idx % N_;
        float v = w2[idx];
        gw2[idx] = gamma[j] * v;
        w2T[c*MID_ + j] = v;
    }
    if (idx < (N_*N_)/4) wmask32[idx] = 0u;
    if (idx < NSTEP_*CTRW_ + 8) ctrall[idx] = 0;       // step ctrs + xcd cnt
    if (idx == 0) *winner = -1;
}

__global__ void k_mask(const int* __restrict__ ids, unsigned char* __restrict__ wmask){
    int i = blockIdx.x*blockDim.x + threadIdx.x;       // 524288 = S_*N_
    if (i < S_*N_){
        int t = i & (N_-1);        // i = k*256 + t  (row-major ids_ary[k][t])
        int c = ids[i];
        wmask[t*N_ + c] = 1;       // benign write race, value always 1
    }
}

// pack byte-mask into bit-mask: wmaskb[t*8 + c/32] bit (c%32)
__global__ void k_pack(const unsigned char* __restrict__ wmask,
                       unsigned int* __restrict__ wmaskb){
    int d = blockIdx.x*blockDim.x + threadIdx.x;       // 2048 total
    if (d < (N_*N_)/32){
        const unsigned int* p = (const unsigned int*)(wmask + d*32);
        unsigned int bits = 0;
        #pragma unroll
        for (int k = 0; k < 8; k++){
            unsigned int v = p[k];
            if (v & 0x000000FFu) bits |= 1u << (k*4 + 0);
            if (v & 0x0000FF00u) bits |= 1u << (k*4 + 1);
            if (v & 0x00FF0000u) bits |= 1u << (k*4 + 2);
            if (v & 0xFF000000u) bits |= 1u << (k*4 + 3);
        }
        wmaskb[d] = bits;
    }
}

__global__ void k_ab(const float* __restrict__ gamma, const float* __restrict__ beta,
                     const float* __restrict__ w2, const float* __restrict__ b2,
                     float* __restrict__ A, float* __restrict__ Bc){
    __shared__ float ra[256], rb[256];
    int c = blockIdx.x, tid = threadIdx.x;
    float a = 0.f, b = 0.f;
    for (int j = tid; j < MID_; j += 256){
        float v = w2[j*N_ + c];
        a += gamma[j]*v;
        b += beta[j]*v;
    }
    ra[tid] = a; rb[tid] = b; __syncthreads();
    for (int off = 128; off > 0; off >>= 1){
        if (tid < off){ ra[tid] += ra[tid+off]; rb[tid] += rb[tid+off]; }
        __syncthreads();
    }
    if (tid == 0){ A[c] = ra[0]; Bc[c] = rb[0] + b2[c]; }
}

// ---------------- exact full-row step (t = 0..2) ----------------

__global__ __launch_bounds__(256) void k_full_rows(
    const float* __restrict__ probs, const float* __restrict__ w1,
    const float* __restrict__ b1, const float* __restrict__ gamma,
    const float* __restrict__ beta, const float* __restrict__ w2T,
    const float* __restrict__ b2, const int* __restrict__ ids,
    float* __restrict__ ps, int t)
{
    __shared__ float prow[8][N_];
    int tid = threadIdx.x;
    int r0 = blockIdx.x * 8;
    for (int i = tid; i < 8*N_; i += 256)
        prow[i>>8][i&255] = probs[(r0 + (i>>8))*N_ + (i&255)];
    __syncthreads();
    int r = tid >> 5, jg = tid & 31;      // 8 rows x 32 threads
    float h[16];
    #pragma unroll
    for (int m = 0; m < 16; m++) h[m] = b1[jg + 32*m];
    for (int c = 0; c < N_; c++){
        float p = prow[r][c];
        const float* w1r = w1 + c*MID_;
        #pragma unroll
        for (int m = 0; m < 16; m++) h[m] = fmaf(p, w1r[jg + 32*m], h[m]);
    }
    float s1 = 0.f, s2 = 0.f;
    #pragma unroll
    for (int m = 0; m < 16; m++){
        float g = gelu_exact(h[m]);
        h[m] = g; s1 += g; s2 += g*g;
    }
    #pragma unroll
    for (int off = 16; off > 0; off >>= 1){
        s1 += __shfl_xor(s1, off, 32);
        s2 += __shfl_xor(s2, off, 32);
    }
    float mu  = s1 * (1.f/MID_);
    float var = s2 * (1.f/MID_) - mu*mu;
    float inv = rsqrtf(var + LN_EPS_);
    int rg = r0 + r;
    int id = ids[rg*N_ + t];
    const float* wrow = w2T + id*MID_;
    float acc = 0.f;
    #pragma unroll
    for (int m = 0; m < 16; m++){
        int j = jg + 32*m;
        float hn = (h[m] - mu)*inv*gamma[j] + beta[j];
        acc = fmaf(hn, wrow[j], acc);
    }
    #pragma unroll
    for (int off = 16; off > 0; off >>= 1) acc += __shfl_xor(acc, off, 32);
    if (jg == 0) ps[rg] = 1.f/(1.f + expf(-(acc + b2[id])));
}

// last-k-wins scatter (numpy fancy-assignment semantics)
__global__ void k_scatter(const int* __restrict__ ids, const float* __restrict__ ps,
                          float* __restrict__ newval, int* __restrict__ wrote, int t){
    __shared__ int lastk[N_];
    int tid = threadIdx.x;
    lastk[tid] = -1;
    __syncthreads();
    for (int k = tid; k < S_; k += 256) atomicMax(&lastk[ids[k*N_ + t]], k);
    __syncthreads();
    int lk = lastk[tid];
    wrote[tid] = (lk >= 0) ? 1 : 0;
    if (lk >= 0) newval[tid] = ps[lk];
}

__global__ void k_apply(float* __restrict__ probs, const float* __restrict__ newval,
                        const int* __restrict__ wrote){
    int idx = blockIdx.x*blockDim.x + threadIdx.x;     // 524288
    int c = idx & (N_-1);
    if (wrote[c]) probs[idx] = newval[c];
}

// ---------------- persistent single-row fast path (t = 3..255) ----------------
// Same-XCD team of 8 (RMW-only election, r5-proven) syncing through the shared
// XCD L2 via never-reused per-step slots + a local-L2 RMW counter. This round:
// LDS-pipe-optimal compute -- all weight reads as bank-even ds_read_b128
// (padded rows), fused P0+P1 via in-wave shuffles, import merged into P4.
// 4 barriers/step (was 6), 128 b128 wave-instr/step (was ~770 b32).

__global__ __launch_bounds__(512) void k_fast(
    const float* __restrict__ w1, const float* __restrict__ b1,
    const float* __restrict__ gw2, const float* __restrict__ A,
    const float* __restrict__ Bc, const unsigned int* __restrict__ wmaskb,
    const float* __restrict__ probs, float* __restrict__ slots,
    int* __restrict__ ctr, int* __restrict__ cnt, int* __restrict__ winner,
    float* __restrict__ commonFinal, int t0)
{
    __shared__ int s_role;
    __shared__ float w1T[64*260];        // [j][c] pad-260: bank = (4j+c)&31
    __shared__ float gw2T[256*68];       // [c][jj] pad-68: bank = (4c+jj)&31
    __shared__ float commonS[N_];        // swizzled: c -> c ^ ((c>>5)<<2)
    __shared__ float gvals[JSL_];
    __shared__ float ws8[16];            // per-wave LN-stat partials
    __shared__ unsigned int wbits[(N_*N_)/32];  // 8 KiB bit-mask

    int tid = threadIdx.x;

    // ---- election: RMW-only, hang-proof (r5-proven) ----
    if (tid == 0){
        int xcd;
        asm volatile("s_getreg_b32 %0, hwreg(HW_REG_XCC_ID)" : "=s"(xcd));
        xcd &= 7;
        int pos = atomicAdd(&cnt[xcd], 1);
        int role = -1;
        if (pos == NB_ - 1){                       // 8th block on this XCD
            int old = atomicCAS(winner, -1, xcd);
            if (old == -1) role = NB_ - 1;
        } else if (pos < NB_ - 1){
            int w;
            while ((w = atomicCAS(winner, -2, -2)) == -1)
                __builtin_amdgcn_s_sleep(2);
            if (w == xcd) role = pos;
        }
        s_role = role;
    }
    __syncthreads();
    int role = s_role;
    if (role < 0) return;
    int j0 = role * JSL_;

    // ---- stage weights into LDS (also flushes this CU's L1 of stale lines) ----
    for (int i = tid; i < 64*256; i += 512){
        int j = i & 63, c = i >> 6;
        w1T[j*260 + c] = w1[c*MID_ + j0 + j];      // global: 64-f coalesced
    }
    for (int i = tid; i < 64*256; i += 512){
        int c = i & 255, jj = i >> 8;
        gw2T[c*68 + jj] = gw2[(j0 + jj)*N_ + c];   // global: 256-f coalesced
    }
    for (int i = tid; i < (N_*N_)/32; i += 512) wbits[i] = wmaskb[i];
    if (tid < N_) commonS[tid ^ (((tid>>5)&7)<<2)] = probs[tid];
    float Ac  = (tid < N_) ? A[tid]  : 0.f;
    float Bcc = (tid < N_) ? Bc[tid] : 0.f;

    int l = tid & 63, w = tid >> 6;
    int cg = l & 7;                      // c-group: c in [cg*32, cg*32+32)
    int jA = (w<<3) + (l>>3);            // block-local j in [0,64)
    float b1v = b1[j0 + jA];
    const float* wbase = &w1T[jA*260 + cg*32];
    const float* grow  = &gw2T[(tid & 255)*68];
    __syncthreads();

    for (int t = t0; t < N_; t++){
        float* slot = slots + (t - t0)*SLOT_F_;    // fresh slot every step
        float* myp  = slot + role*BSTRIDE_;
        // Phase A: h_j partials (b128, bank-even) + shuffle-reduce + gelu + stats
        {
            float a0=0.f, a1=0.f, a2=0.f, a3=0.f;
            #pragma unroll
            for (int cc = 0; cc < 8; cc++){
                f32x4 wv = *(const f32x4*)(wbase + cc*4);
                f32x4 cv = *(const f32x4*)(&commonS[(cg*32 + cc*4) ^ (cg<<2)]);
                a0 = fmaf(wv.x, cv.x, a0); a1 = fmaf(wv.y, cv.y, a1);
                a2 = fmaf(wv.z, cv.z, a2); a3 = fmaf(wv.w, cv.w, a3);
            }
            float hp = (a0+a1) + (a2+a3);
            hp += __shfl_xor(hp, 1);     // reduce over cg (lane bits 0-2)
            hp += __shfl_xor(hp, 2);
            hp += __shfl_xor(hp, 4);
            float g = gelu_exact(hp + b1v);
            float s1 = g, s2 = g*g;
            s1 += __shfl_xor(s1, 8);  s2 += __shfl_xor(s2, 8);   // over j (bits 3-5)
            s1 += __shfl_xor(s1, 16); s2 += __shfl_xor(s2, 16);
            s1 += __shfl_xor(s1, 32); s2 += __shfl_xor(s2, 32);
            if (l == 0){ ws8[w*2] = s1; ws8[w*2+1] = s2; }
            if (cg == 0) gvals[jA] = g;
        }
        __syncthreads();
        // Phase B: partial matvec (b128 gw2 rows + b128 broadcast gvals); export
        if (tid < N_){
            float p0=0.f, p1=0.f, p2=0.f, p3=0.f;
            #pragma unroll
            for (int k = 0; k < 16; k++){
                f32x4 wv = *(const f32x4*)(grow + k*4);
                f32x4 gv = *(const f32x4*)(&gvals[k*4]);
                p0 = fmaf(wv.x, gv.x, p0); p1 = fmaf(wv.y, gv.y, p1);
                p2 = fmaf(wv.z, gv.z, p2); p3 = fmaf(wv.w, gv.w, p3);
            }
            myp[tid] = (p0+p1) + (p2+p3);
        }
        if (tid == 0){
            float S1 = 0.f, S2 = 0.f;
            #pragma unroll
            for (int ww = 0; ww < 8; ww++){ S1 += ws8[ww*2]; S2 += ws8[ww*2+1]; }
            f32x2 st; st.x = S1; st.y = S2;
            *(f32x2*)(myp + 256) = st;
        }
        asm volatile("s_waitcnt vmcnt(0)" ::: "memory");  // own stores acked at L2
        __syncthreads();                                   // all waves drained
        // publish + wait: local-L2 RMW counter (r5-proven)
        int* c_t = ctr + (t - t0)*CTRW_;
        if (tid == 0){
            atomic_inc_l2(c_t);
            while (atomic_read_l2(c_t) < NB_) {}
        }
        __syncthreads();
        // P4 (merged import+finish): plain loads of the fresh slot
        if (tid < N_){
            const float* sp = slot;
            float s1 = 0.f;
            #pragma unroll
            for (int bb = 0; bb < NB_; bb++) s1 += sp[bb*BSTRIDE_ + tid];
            float S1 = 0.f, S2 = 0.f;
            #pragma unroll
            for (int bb = 0; bb < NB_; bb++){
                f32x2 st = *(const f32x2*)(sp + bb*BSTRIDE_ + 256);
                S1 += st.x; S2 += st.y;
            }
            float mu  = S1 * (1.f/MID_);
            float var = S2 * (1.f/MID_) - mu*mu;
            float inv = rsqrtf(var + LN_EPS_);
            float s = inv*(s1 - mu*Ac) + Bcc;
            float o = 1.f/(1.f + expf(-s));
            if ((wbits[(t<<3) + (tid>>5)] >> (tid&31)) & 1u)
                commonS[tid ^ (((tid>>5)&7)<<2)] = o;
        }
        __syncthreads();
    }
    if (role == 0 && tid < N_)
        commonFinal[tid] = commonS[tid ^ (((tid>>5)&7)<<2)];
}

__global__ void k_out(const float* __restrict__ commonFinal, float* __restrict__ out){
    int idx = blockIdx.x*blockDim.x + threadIdx.x;     // 524288
    out[idx] = commonFinal[idx & (N_-1)];
}

// ---------------- launch ----------------

extern "C" void kernel_launch(void* const* d_in, const int* in_sizes, int n_in,
                              void* d_out, int out_size, void* d_ws, size_t ws_size,
                              hipStream_t stream)
{
    const float* xs    = (const float*)d_in[0];
    const int*   ids   = (const int*)  d_in[1];
    const float* w1    = (const float*)d_in[2];
    const float* b1    = (const float*)d_in[3];
    const float* gamma = (const float*)d_in[4];
    const float* beta  = (const float*)d_in[5];
    const float* w2    = (const float*)d_in[6];
    const float* b2    = (const float*)d_in[7];
    float* out = (float*)d_out;

    float* ws      = (float*)d_ws;
    float* probs   = ws;                     // 524288 f32
    // slots alias probs[2048:] + w2T (both dead during k_fast):
    float* slots   = ws + 2048;              // 253*2304 = 582912 f32, ends 584960
    float* w2T     = ws + 524288;            // 131072 (used only before k_fast)
    float* gw2     = ws + 655360;            // 131072
    float* A       = ws + 786432;            // 256
    float* Bc      = ws + 786688;            // 256
    float* ps      = ws + 786944;            // 2048
    float* newval  = ws + 788992;            // 256
    int*   wrote   = (int*)(ws + 789248);    // 256
    unsigned char* wmask = (unsigned char*)(ws + 789504);   // 65536 B -> ends 805888
    unsigned int* wmaskb = (unsigned int*)(ws + 805888);    // 2048 -> ends 807936
    int*   ctrall  = (int*)(ws + 807936);    // 253*32 + 9 ints
    int*   ctr     = ctrall;                 // per-step counters
    int*   cnt     = ctrall + NSTEP_*CTRW_;  // 8 per-XCD counters
    int*   winner  = cnt + 8;                // 1
    float* commonFinal = ws + 816064;        // 256 -> ends 816320 (~3.27 MB)

    k_init<<<2048, 256, 0, stream>>>(xs, gamma, w2, probs, w2T, gw2,
                                     (unsigned int*)wmask, ctrall, winner);
    k_mask<<<2048, 256, 0, stream>>>(ids, wmask);
    k_ab<<<256, 256, 0, stream>>>(gamma, beta, w2, b2, A, Bc);
    k_pack<<<8, 256, 0, stream>>>(wmask, wmaskb);

    for (int t = 0; t < 3; t++){
        k_full_rows<<<256, 256, 0, stream>>>(probs, w1, b1, gamma, beta, w2T, b2,
                                             ids, ps, t);
        k_scatter<<<1, 256, 0, stream>>>(ids, ps, newval, wrote, t);
        k_apply<<<2048, 256, 0, stream>>>(probs, newval, wrote);
    }

    k_fast<<<NBLK_, 512, 0, stream>>>(w1, b1, gw2, A, Bc, wmaskb, probs, slots,
                                      ctr, cnt, winner, commonFinal, 3);
    k_out<<<2048, 256, 0, stream>>>(commonFinal, out);
}